// Round 1
// baseline (461.293 us; speedup 1.0000x reference)
//
#include <hip/hip_runtime.h>
#include <stdint.h>

#define D_MODEL 1024
#define NH      16
#define BB      4
#define TT      2048
#define MROWS   (BB * TT)   // 8192

typedef __attribute__((ext_vector_type(8))) short bf16x8;
typedef __attribute__((ext_vector_type(4))) float f32x4;

__device__ __forceinline__ unsigned short f2bf(float f) {
    union { float f; unsigned int u; } v; v.f = f;
    unsigned int r = v.u + 0x7fffu + ((v.u >> 16) & 1u);   // RNE
    return (unsigned short)(r >> 16);
}

__device__ __forceinline__ void gload_lds16(const unsigned short* g, unsigned short* l) {
    __builtin_amdgcn_global_load_lds(
        (const __attribute__((address_space(1))) void*)g,
        (__attribute__((address_space(3))) void*)l,
        16, 0, 0);
}

// ---------------- convert x: fp32 -> bf16 ----------------
__global__ void convert_x_kernel(const float* __restrict__ x, unsigned short* __restrict__ xb) {
    int i = blockIdx.x * 256 + threadIdx.x;     // one float4 per thread
    float4 v = ((const float4*)x)[i];
    ushort4 o;
    o.x = f2bf(v.x); o.y = f2bf(v.y); o.z = f2bf(v.z); o.w = f2bf(v.w);
    ((ushort4*)xb)[i] = o;
}

// ---------------- transpose+convert weights: [K,N] fp32 -> [N,K] bf16 ----------------
__global__ void transpose_w_kernel(const float* __restrict__ wq, const float* __restrict__ wk,
                                   const float* __restrict__ wv, const float* __restrict__ wo,
                                   unsigned short* tq, unsigned short* tk,
                                   unsigned short* tv, unsigned short* to_) {
    const float* src; unsigned short* dst;
    switch (blockIdx.z) {
        case 0:  src = wq; dst = tq; break;
        case 1:  src = wk; dst = tk; break;
        case 2:  src = wv; dst = tv; break;
        default: src = wo; dst = to_; break;
    }
    __shared__ float tile[32][33];
    int tx = threadIdx.x & 31, ty = threadIdx.x >> 5;   // 32 x 8
    int k0 = blockIdx.y * 32, n0 = blockIdx.x * 32;
    #pragma unroll
    for (int i = 0; i < 4; ++i)
        tile[ty + i * 8][tx] = src[(k0 + ty + i * 8) * D_MODEL + n0 + tx];
    __syncthreads();
    #pragma unroll
    for (int i = 0; i < 4; ++i)
        dst[(n0 + ty + i * 8) * D_MODEL + k0 + tx] = f2bf(tile[tx][ty + i * 8]);
}

// ---------------- shared 128x128 GEMM mainloop (A[M,K] * Bt[N,K]^T) ----------------
__device__ __forceinline__ void gemm_mainloop(const unsigned short* __restrict__ A,
                                              const unsigned short* __restrict__ Bt,
                                              int m0, int n0,
                                              unsigned short* As, unsigned short* Bs,
                                              f32x4 acc[4][4]) {
    const int tid = threadIdx.x;
    const int lane = tid & 63, wave = tid >> 6;
    const int wm = (wave >> 1) * 64, wn = (wave & 1) * 64;
    const int l15 = lane & 15, quad = lane >> 4;
    const int row = tid >> 2, colb = (tid & 3) * 8;
    const unsigned short* Ag = A + (size_t)(m0 + row) * D_MODEL + colb;
    const unsigned short* Bg = Bt + (size_t)(n0 + row) * D_MODEL + colb;
    unsigned short* AsW = As + wave * 512;   // wave-uniform LDS base (1024 B per wave)
    unsigned short* BsW = Bs + wave * 512;
    for (int k0 = 0; k0 < D_MODEL; k0 += 32) {
        __syncthreads();
        gload_lds16(Ag + k0, AsW);
        gload_lds16(Ag + k0 + (size_t)64 * D_MODEL, AsW + 2048);
        gload_lds16(Bg + k0, BsW);
        gload_lds16(Bg + k0 + (size_t)64 * D_MODEL, BsW + 2048);
        __syncthreads();
        bf16x8 af[4], bfr[4];
        #pragma unroll
        for (int mt = 0; mt < 4; ++mt)
            af[mt] = *(const bf16x8*)(As + (wm + mt * 16 + l15) * 32 + quad * 8);
        #pragma unroll
        for (int nt = 0; nt < 4; ++nt)
            bfr[nt] = *(const bf16x8*)(Bs + (wn + nt * 16 + l15) * 32 + quad * 8);
        #pragma unroll
        for (int mt = 0; mt < 4; ++mt)
            #pragma unroll
            for (int nt = 0; nt < 4; ++nt)
                acc[mt][nt] = __builtin_amdgcn_mfma_f32_16x16x32_bf16(af[mt], bfr[nt], acc[mt][nt], 0, 0, 0);
    }
}

// ---------------- QKV projection GEMM: writes [BH, T, 64] bf16, Q pre-scaled ----------------
__global__ __launch_bounds__(256, 2) void gemm_qkv_kernel(
        const unsigned short* __restrict__ Xb,
        const unsigned short* __restrict__ Wtq, const unsigned short* __restrict__ Wtk,
        const unsigned short* __restrict__ Wtv,
        const float* __restrict__ bq, const float* __restrict__ bk, const float* __restrict__ bv,
        unsigned short* __restrict__ Qo, unsigned short* __restrict__ Ko, unsigned short* __restrict__ Vo) {
    __shared__ unsigned short As[128 * 32], Bs[128 * 32];
    const unsigned short* Wt; const float* bias; unsigned short* Out; float scale;
    if (blockIdx.z == 0)      { Wt = Wtq; bias = bq; Out = Qo; scale = 0.125f; }
    else if (blockIdx.z == 1) { Wt = Wtk; bias = bk; Out = Ko; scale = 1.f; }
    else                      { Wt = Wtv; bias = bv; Out = Vo; scale = 1.f; }
    int m0 = blockIdx.y * 128, n0 = blockIdx.x * 128;
    f32x4 acc[4][4];
    #pragma unroll
    for (int mt = 0; mt < 4; ++mt)
        #pragma unroll
        for (int nt = 0; nt < 4; ++nt)
            acc[mt][nt] = (f32x4){0.f, 0.f, 0.f, 0.f};
    gemm_mainloop(Xb, Wt, m0, n0, As, Bs, acc);
    const int tid = threadIdx.x, lane = tid & 63, wave = tid >> 6;
    const int wm = (wave >> 1) * 64, wn = (wave & 1) * 64, l15 = lane & 15, quad = lane >> 4;
    #pragma unroll
    for (int nt = 0; nt < 4; ++nt) {
        int gn = n0 + wn + nt * 16 + l15;
        float bv_ = bias[gn];
        int h = gn >> 6, dd = gn & 63;
        #pragma unroll
        for (int mt = 0; mt < 4; ++mt) {
            #pragma unroll
            for (int r = 0; r < 4; ++r) {
                int gm = m0 + wm + mt * 16 + quad * 4 + r;
                int b = gm >> 11, t = gm & 2047;
                float v = (acc[mt][nt][r] + bv_) * scale;
                Out[(size_t)((b * NH + h) * TT + t) * 64 + dd] = f2bf(v);
            }
        }
    }
}

// ---------------- output projection GEMM: fp32 out + bias ----------------
__global__ __launch_bounds__(256, 2) void gemm_out_kernel(
        const unsigned short* __restrict__ Ob, const unsigned short* __restrict__ Wto,
        const float* __restrict__ bo, float* __restrict__ out) {
    __shared__ unsigned short As[128 * 32], Bs[128 * 32];
    int m0 = blockIdx.y * 128, n0 = blockIdx.x * 128;
    f32x4 acc[4][4];
    #pragma unroll
    for (int mt = 0; mt < 4; ++mt)
        #pragma unroll
        for (int nt = 0; nt < 4; ++nt)
            acc[mt][nt] = (f32x4){0.f, 0.f, 0.f, 0.f};
    gemm_mainloop(Ob, Wto, m0, n0, As, Bs, acc);
    const int tid = threadIdx.x, lane = tid & 63, wave = tid >> 6;
    const int wm = (wave >> 1) * 64, wn = (wave & 1) * 64, l15 = lane & 15, quad = lane >> 4;
    #pragma unroll
    for (int nt = 0; nt < 4; ++nt) {
        int gn = n0 + wn + nt * 16 + l15;
        float bv_ = bo[gn];
        #pragma unroll
        for (int mt = 0; mt < 4; ++mt) {
            #pragma unroll
            for (int r = 0; r < 4; ++r) {
                int gm = m0 + wm + mt * 16 + quad * 4 + r;
                out[(size_t)gm * D_MODEL + gn] = acc[mt][nt][r] + bv_;
            }
        }
    }
}

// ---------------- causal flash attention ----------------
// Q,K,V: [BH, T, 64] bf16 (Q pre-scaled by 1/8). O: [8192, 1024] bf16 (heads merged).
__global__ __launch_bounds__(256, 2) void flash_kernel(
        const unsigned short* __restrict__ Q, const unsigned short* __restrict__ K,
        const unsigned short* __restrict__ V, unsigned short* __restrict__ O) {
    __shared__ unsigned short Qs[128 * 72];    // Q tile, padded stride 72
    __shared__ unsigned short KPs[128 * 136];  // union: K tile (stride 72) then P (stride 136)
    __shared__ unsigned short Vt[64 * 136];    // V transposed [d][key], padded stride 136
    const int qt = blockIdx.x, bh = blockIdx.y;
    const int q0 = qt * 128;
    const int tid = threadIdx.x, lane = tid & 63, wave = tid >> 6;
    const int l15 = lane & 15, quad = lane >> 4;
    const int mbase = wave * 32;               // this wave's 32 query rows
    const unsigned short* Qb = Q + (size_t)bh * (TT * 64) + (size_t)q0 * 64;
    const unsigned short* Kb = K + (size_t)bh * (TT * 64);
    const unsigned short* Vb = V + (size_t)bh * (TT * 64);

    #pragma unroll
    for (int p = 0; p < 4; ++p) {
        int s = tid + p * 256, row = s >> 3, c8 = (s & 7) * 8;
        *(uint4*)&Qs[row * 72 + c8] = *(const uint4*)(Qb + row * 64 + c8);
    }

    float m_run[2][4], l_run[2][4];
    f32x4 acc[2][4];
    #pragma unroll
    for (int mt = 0; mt < 2; ++mt) {
        #pragma unroll
        for (int r = 0; r < 4; ++r) { m_run[mt][r] = -__builtin_inff(); l_run[mt][r] = 0.f; }
        #pragma unroll
        for (int nt = 0; nt < 4; ++nt) acc[mt][nt] = (f32x4){0.f, 0.f, 0.f, 0.f};
    }

    for (int kt = 0; kt <= qt; ++kt) {
        __syncthreads();   // prior iter's P/V reads done; safe to restage
        const unsigned short* Kg = Kb + (size_t)kt * 128 * 64;
        const unsigned short* Vg = Vb + (size_t)kt * 128 * 64;
        #pragma unroll
        for (int p = 0; p < 4; ++p) {
            int s = tid + p * 256, row = s >> 3, c8 = (s & 7) * 8;
            *(uint4*)&KPs[row * 72 + c8] = *(const uint4*)(Kg + row * 64 + c8);
        }
        #pragma unroll
        for (int p = 0; p < 4; ++p) {
            int s = tid + p * 256, key = s >> 3, c8 = (s & 7) * 8;
            uint4 raw = *(const uint4*)(Vg + key * 64 + c8);
            const unsigned short* pv = (const unsigned short*)&raw;
            #pragma unroll
            for (int j = 0; j < 8; ++j) Vt[(c8 + j) * 136 + key] = pv[j];
        }
        __syncthreads();

        // S = Q * K^T  (2 k-steps over d=64)
        f32x4 sf[2][8];
        #pragma unroll
        for (int mt = 0; mt < 2; ++mt)
            #pragma unroll
            for (int nt = 0; nt < 8; ++nt) sf[mt][nt] = (f32x4){0.f, 0.f, 0.f, 0.f};
        #pragma unroll
        for (int kk = 0; kk < 2; ++kk) {
            bf16x8 aq[2];
            #pragma unroll
            for (int mt = 0; mt < 2; ++mt)
                aq[mt] = *(const bf16x8*)&Qs[(mbase + mt * 16 + l15) * 72 + kk * 32 + quad * 8];
            #pragma unroll
            for (int nt = 0; nt < 8; ++nt) {
                bf16x8 bk_ = *(const bf16x8*)&KPs[(nt * 16 + l15) * 72 + kk * 32 + quad * 8];
                #pragma unroll
                for (int mt = 0; mt < 2; ++mt)
                    sf[mt][nt] = __builtin_amdgcn_mfma_f32_16x16x32_bf16(aq[mt], bk_, sf[mt][nt], 0, 0, 0);
            }
        }
        if (kt == qt) {   // diagonal tile causal mask (local indices: same 128-base)
            #pragma unroll
            for (int mt = 0; mt < 2; ++mt)
                #pragma unroll
                for (int nt = 0; nt < 8; ++nt)
                    #pragma unroll
                    for (int r = 0; r < 4; ++r) {
                        int qi = mbase + mt * 16 + quad * 4 + r;
                        int ki = nt * 16 + l15;
                        if (ki > qi) sf[mt][nt][r] = -1e30f;
                    }
        }

        // online softmax (state per (quad-row) kept redundantly in registers)
        #pragma unroll
        for (int mt = 0; mt < 2; ++mt) {
            #pragma unroll
            for (int r = 0; r < 4; ++r) {
                float rm = sf[mt][0][r];
                #pragma unroll
                for (int nt = 1; nt < 8; ++nt) rm = fmaxf(rm, sf[mt][nt][r]);
                rm = fmaxf(rm, __shfl_xor(rm, 1));
                rm = fmaxf(rm, __shfl_xor(rm, 2));
                rm = fmaxf(rm, __shfl_xor(rm, 4));
                rm = fmaxf(rm, __shfl_xor(rm, 8));
                float mn = fmaxf(m_run[mt][r], rm);
                float al = __expf(m_run[mt][r] - mn);
                float rs = 0.f;
                #pragma unroll
                for (int nt = 0; nt < 8; ++nt) {
                    float pv = __expf(sf[mt][nt][r] - mn);
                    sf[mt][nt][r] = pv; rs += pv;
                }
                rs += __shfl_xor(rs, 1); rs += __shfl_xor(rs, 2);
                rs += __shfl_xor(rs, 4); rs += __shfl_xor(rs, 8);
                l_run[mt][r] = l_run[mt][r] * al + rs;
                m_run[mt][r] = mn;
                #pragma unroll
                for (int d4 = 0; d4 < 4; ++d4) acc[mt][d4][r] *= al;
            }
        }
        __syncthreads();   // all waves done reading K tile -> safe to overwrite with P

        // write P (C/D layout positions) into LDS, bf16
        #pragma unroll
        for (int mt = 0; mt < 2; ++mt)
            #pragma unroll
            for (int nt = 0; nt < 8; ++nt)
                #pragma unroll
                for (int r = 0; r < 4; ++r)
                    KPs[(mbase + mt * 16 + quad * 4 + r) * 136 + nt * 16 + l15] = f2bf(sf[mt][nt][r]);
        __syncthreads();

        // O += P * V  (4 k-steps over 128 keys)
        #pragma unroll
        for (int kk = 0; kk < 4; ++kk) {
            bf16x8 pa[2];
            #pragma unroll
            for (int mt = 0; mt < 2; ++mt)
                pa[mt] = *(const bf16x8*)&KPs[(mbase + mt * 16 + l15) * 136 + kk * 32 + quad * 8];
            #pragma unroll
            for (int nt = 0; nt < 4; ++nt) {
                bf16x8 vb_ = *(const bf16x8*)&Vt[(nt * 16 + l15) * 136 + kk * 32 + quad * 8];
                #pragma unroll
                for (int mt = 0; mt < 2; ++mt)
                    acc[mt][nt] = __builtin_amdgcn_mfma_f32_16x16x32_bf16(pa[mt], vb_, acc[mt][nt], 0, 0, 0);
            }
        }
    }

    const int b = bh >> 4, h = bh & 15;
    #pragma unroll
    for (int mt = 0; mt < 2; ++mt)
        #pragma unroll
        for (int nt = 0; nt < 4; ++nt)
            #pragma unroll
            for (int r = 0; r < 4; ++r) {
                int gm = b * TT + q0 + mbase + mt * 16 + quad * 4 + r;
                int gn = h * 64 + nt * 16 + l15;
                O[(size_t)gm * D_MODEL + gn] = f2bf(acc[mt][nt][r] / l_run[mt][r]);
            }
}

extern "C" void kernel_launch(void* const* d_in, const int* in_sizes, int n_in,
                              void* d_out, int out_size, void* d_ws, size_t ws_size,
                              hipStream_t stream) {
    const float* x  = (const float*)d_in[0];
    // d_in[1] = mask (tril causal) — causality is applied analytically in flash_kernel
    const float* wq = (const float*)d_in[2];
    const float* bq = (const float*)d_in[3];
    const float* wk = (const float*)d_in[4];
    const float* bk = (const float*)d_in[5];
    const float* wv = (const float*)d_in[6];
    const float* bv = (const float*)d_in[7];
    const float* wo = (const float*)d_in[8];
    const float* bo = (const float*)d_in[9];

    char* ws = (char*)d_ws;
    unsigned short* Xb  = (unsigned short*)ws;                         // 16 MB (reused for O)
    unsigned short* Wtq = (unsigned short*)(ws + (size_t)(16 << 20));  // 2 MB each
    unsigned short* Wtk = Wtq + (size_t)D_MODEL * D_MODEL;
    unsigned short* Wtv = Wtk + (size_t)D_MODEL * D_MODEL;
    unsigned short* Wto = Wtv + (size_t)D_MODEL * D_MODEL;
    unsigned short* Qb  = Wto + (size_t)D_MODEL * D_MODEL;             // 16 MB each
    unsigned short* Kb  = Qb + (size_t)MROWS * D_MODEL;
    unsigned short* Vb  = Kb + (size_t)MROWS * D_MODEL;
    unsigned short* Ob  = Xb;   // alias: X no longer needed after QKV GEMM

    convert_x_kernel<<<(MROWS * D_MODEL) / (256 * 4), 256, 0, stream>>>(x, Xb);
    transpose_w_kernel<<<dim3(32, 32, 4), 256, 0, stream>>>(wq, wk, wv, wo, Wtq, Wtk, Wtv, Wto);
    gemm_qkv_kernel<<<dim3(D_MODEL / 128, MROWS / 128, 3), 256, 0, stream>>>(
        Xb, Wtq, Wtk, Wtv, bq, bk, bv, Qb, Kb, Vb);
    flash_kernel<<<dim3(TT / 128, BB * NH), 256, 0, stream>>>(Qb, Kb, Vb, Ob);
    gemm_out_kernel<<<dim3(D_MODEL / 128, MROWS / 128), 256, 0, stream>>>(Ob, Wto, bo, (float*)d_out);
}